// Round 1
// baseline (720.563 us; speedup 1.0000x reference)
//
#include <hip/hip_runtime.h>

typedef unsigned short ushort_t;
typedef __attribute__((ext_vector_type(8))) short s8v;
typedef __attribute__((ext_vector_type(4))) float f4v;

__device__ __forceinline__ float b2f(ushort_t h) {
    union { unsigned u; float f; } c; c.u = ((unsigned)h) << 16; return c.f;
}
__device__ __forceinline__ ushort_t f2b(float f) {
    union { float f; unsigned u; } c; c.f = f;
    unsigned u = c.u;
    return (ushort_t)((u + 0x7fffu + ((u >> 16) & 1u)) >> 16);
}

__device__ __forceinline__ void glds16(const void* g, void* l) {
    __builtin_amdgcn_global_load_lds(
        (const __attribute__((address_space(1))) void*)g,
        (__attribute__((address_space(3))) void*)l, 16, 0, 0);
}

// ---------------- weight transpose f32 [K,N] -> bf16 [N,K] ----------------
__global__ __launch_bounds__(256) void trans_k(const float* __restrict__ W,
                                               ushort_t* __restrict__ Wt,
                                               int K, int N) {
    __shared__ float tile[64][65];
    int k0 = blockIdx.x * 64, n0 = blockIdx.y * 64;
    int t = threadIdx.x;
    int c = t & 63, r4 = t >> 6;
#pragma unroll
    for (int i = 0; i < 16; ++i) {
        int r = i * 4 + r4;
        tile[r][c] = W[(size_t)(k0 + r) * N + n0 + c];
    }
    __syncthreads();
#pragma unroll
    for (int i = 0; i < 16; ++i) {
        int r = i * 4 + r4;
        Wt[(size_t)(n0 + r) * K + k0 + c] = f2b(tile[c][r]);
    }
}

// ---------------- norm: alpha*(x-mu)/(std_ddof1+eps)+bias -> bf16 --------
__global__ __launch_bounds__(256) void norm_k(const float* __restrict__ x,
                                              const float* __restrict__ al,
                                              const float* __restrict__ be,
                                              ushort_t* __restrict__ out) {
    int row = blockIdx.x;
    const float4* xr = (const float4*)(x + (size_t)row * 1024);
    float4 v = xr[threadIdx.x];
    float s = v.x + v.y + v.z + v.w;
    float q = v.x * v.x + v.y * v.y + v.z * v.z + v.w * v.w;
#pragma unroll
    for (int o = 32; o > 0; o >>= 1) {
        s += __shfl_down(s, o);
        q += __shfl_down(q, o);
    }
    __shared__ float ss[4], qq[4];
    int lane = threadIdx.x & 63, wv = threadIdx.x >> 6;
    if (lane == 0) { ss[wv] = s; qq[wv] = q; }
    __syncthreads();
    s = ss[0] + ss[1] + ss[2] + ss[3];
    q = qq[0] + qq[1] + qq[2] + qq[3];
    float mu = s * (1.f / 1024.f);
    float var = (q - 1024.f * mu * mu) * (1.f / 1023.f);
    var = fmaxf(var, 0.f);
    float inv = 1.f / (sqrtf(var) + 1e-6f);
    float4 a4 = ((const float4*)al)[threadIdx.x];
    float4 b4 = ((const float4*)be)[threadIdx.x];
    ushort4 o4;
    o4.x = f2b(a4.x * (v.x - mu) * inv + b4.x);
    o4.y = f2b(a4.y * (v.y - mu) * inv + b4.y);
    o4.z = f2b(a4.z * (v.z - mu) * inv + b4.z);
    o4.w = f2b(a4.w * (v.w - mu) * inv + b4.w);
    ((ushort4*)(out + (size_t)row * 1024))[threadIdx.x] = o4;
}

// ---------------- GLU + mask: g = a*sigmoid(b)*mask -----------------------
__global__ __launch_bounds__(256) void glu_k(const ushort_t* __restrict__ t1,
                                             const int* __restrict__ mask,
                                             ushort_t* __restrict__ g) {
    int i = blockIdx.x * 256 + threadIdx.x;
    int row = i >> 7;           // 128 chunks of 8 per row
    int cc = (i & 127) << 3;
    int b = row >> 10, s = row & 1023;
    size_t base = (size_t)row * 2048;
    s8v va = *(const s8v*)(t1 + base + cc);
    s8v vb = *(const s8v*)(t1 + base + 1024 + cc);
    float mval = (mask[b * 1024 + s] == 0) ? 0.f : 1.f;
    s8v ov;
#pragma unroll
    for (int j = 0; j < 8; ++j) {
        float a = b2f((ushort_t)va[j]);
        float xx = b2f((ushort_t)vb[j]);
        float sg = 1.f / (1.f + __expf(-xx));
        ov[j] = (short)f2b(a * sg * mval);
    }
    *(s8v*)(g + (size_t)row * 1024 + cc) = ov;
}

// ---------------- depthwise lightconv K=3, softmax weights ----------------
__global__ __launch_bounds__(256) void conv_k(const ushort_t* __restrict__ g,
                                              const float* __restrict__ cw,
                                              ushort_t* __restrict__ out) {
    int i = blockIdx.x * 256 + threadIdx.x;
    int row = i >> 7;           // b*1024 + s
    int cc = (i & 127) << 3;
    int s = row & 1023;
    int head = cc >> 6;
    float w0 = cw[head * 3 + 0], w1 = cw[head * 3 + 1], w2 = cw[head * 3 + 2];
    float mx = fmaxf(w0, fmaxf(w1, w2));
    float e0 = __expf(w0 - mx), e1 = __expf(w1 - mx), e2 = __expf(w2 - mx);
    float inv = 1.f / (e0 + e1 + e2);
    w0 = e0 * inv; w1 = e1 * inv; w2 = e2 * inv;
    size_t base = (size_t)row * 1024 + cc;
    s8v z = {0, 0, 0, 0, 0, 0, 0, 0};
    s8v vm = (s > 0)    ? *(const s8v*)(g + base - 1024) : z;
    s8v v0 = *(const s8v*)(g + base);
    s8v vp = (s < 1023) ? *(const s8v*)(g + base + 1024) : z;
    s8v ov;
#pragma unroll
    for (int j = 0; j < 8; ++j) {
        float r = w0 * b2f((ushort_t)vm[j]) + w1 * b2f((ushort_t)v0[j]) +
                  w2 * b2f((ushort_t)vp[j]);
        ov[j] = (short)f2b(r);
    }
    *(s8v*)(out + base) = ov;
}

// ---------------- bf16 GEMM, 128x128 tile, BK=32, m97 structure ----------
// A [M,K] bf16 rm; Bt [N,K] bf16 rm (pre-transposed weights).
// EPI: 0 = bf16 out (+bias); 1 = f32 out (+bias+res); 2 = bf16 relu(+bias)
template <int EPI>
__global__ __launch_bounds__(256) void gemm_k(const ushort_t* __restrict__ A,
                                              const ushort_t* __restrict__ Bt,
                                              const float* __restrict__ bias,
                                              const float* res, float* outf,
                                              ushort_t* outb, int N, int K) {
    __shared__ char smem[16384] __attribute__((aligned(16)));
    const int nbn = N >> 7;
    const int bm = blockIdx.x / nbn;
    const int bn = blockIdx.x % nbn;
    const int t = threadIdx.x;
    const int lane = t & 63;
    const int wv = t >> 6;
    const int wm = wv >> 1, wn = wv & 1;
    const int lr = lane & 15, lk = lane >> 4;

    // staging: 512 slots of 16B per tile; thread t handles slots t, t+256
    const int s0 = t, s1 = t + 256;
    const int r0 = s0 >> 2, r1 = s1 >> 2;
    const int c0 = (s0 & 3) << 4, c1 = (s1 & 3) << 4;
    // both-sides XOR swizzle: lds[row*64 + q] holds row-bytes (q ^ swz(row))
    const int cx0 = c0 ^ (((r0 >> 1) & 3) << 4);
    const int cx1 = c1 ^ (((r1 >> 1) & 3) << 4);
    const ushort_t* gA0 = A + (size_t)(bm * 128 + r0) * K + (cx0 >> 1);
    const ushort_t* gA1 = A + (size_t)(bm * 128 + r1) * K + (cx1 >> 1);
    const ushort_t* gB0 = Bt + (size_t)(bn * 128 + r0) * K + (cx0 >> 1);
    const ushort_t* gB1 = Bt + (size_t)(bn * 128 + r1) * K + (cx1 >> 1);
    char* lA0 = smem + s0 * 16;
    char* lA1 = smem + s1 * 16;
    char* lB0 = smem + 8192 + s0 * 16;
    char* lB1 = smem + 8192 + s1 * 16;

    // fragment ds_read offsets (swizzled), constant across K-steps
    int offA[4], offB[4];
#pragma unroll
    for (int m = 0; m < 4; ++m) {
        int ra = wm * 64 + m * 16 + lr;
        offA[m] = ra * 64 + ((lk * 16) ^ (((ra >> 1) & 3) << 4));
        int rb = wn * 64 + m * 16 + lr;
        offB[m] = 8192 + rb * 64 + ((lk * 16) ^ (((rb >> 1) & 3) << 4));
    }

    f4v acc[4][4];
#pragma unroll
    for (int m = 0; m < 4; ++m)
#pragma unroll
        for (int n = 0; n < 4; ++n) acc[m][n] = f4v{0.f, 0.f, 0.f, 0.f};

    const int nk = K >> 5;
    for (int kt = 0; kt < nk; ++kt) {
        glds16(gA0 + kt * 32, lA0);
        glds16(gA1 + kt * 32, lA1);
        glds16(gB0 + kt * 32, lB0);
        glds16(gB1 + kt * 32, lB1);
        __syncthreads();
        s8v av[4], bv[4];
#pragma unroll
        for (int m = 0; m < 4; ++m) av[m] = *(const s8v*)(smem + offA[m]);
#pragma unroll
        for (int n = 0; n < 4; ++n) bv[n] = *(const s8v*)(smem + offB[n]);
#pragma unroll
        for (int m = 0; m < 4; ++m)
#pragma unroll
            for (int n = 0; n < 4; ++n)
                acc[m][n] = __builtin_amdgcn_mfma_f32_16x16x32_bf16(
                    av[m], bv[n], acc[m][n], 0, 0, 0);
        __syncthreads();
    }

#pragma unroll
    for (int n = 0; n < 4; ++n) {
        int gcol = bn * 128 + wn * 64 + n * 16 + lr;
        float bb = bias[gcol];
#pragma unroll
        for (int m = 0; m < 4; ++m) {
#pragma unroll
            for (int r = 0; r < 4; ++r) {
                int grow = bm * 128 + wm * 64 + m * 16 + lk * 4 + r;
                size_t oi = (size_t)grow * N + gcol;
                float v = acc[m][n][r] + bb;
                if (EPI == 1) {
                    outf[oi] = v + res[oi];
                } else if (EPI == 2) {
                    outb[oi] = f2b(fmaxf(v, 0.f));
                } else {
                    outb[oi] = f2b(v);
                }
            }
        }
    }
}

extern "C" void kernel_launch(void* const* d_in, const int* in_sizes, int n_in,
                              void* d_out, int out_size, void* d_ws, size_t ws_size,
                              hipStream_t stream) {
    const float* x      = (const float*)d_in[0];
    const int*   mask   = (const int*)d_in[1];
    const float* alpha1 = (const float*)d_in[2];
    const float* bias1  = (const float*)d_in[3];
    const float* alpha2 = (const float*)d_in[4];
    const float* bias2  = (const float*)d_in[5];
    const float* W_l1   = (const float*)d_in[6];
    const float* b_l1   = (const float*)d_in[7];
    const float* conv_w = (const float*)d_in[8];
    const float* W_l2   = (const float*)d_in[9];
    const float* b_l2   = (const float*)d_in[10];
    const float* W_ff1  = (const float*)d_in[11];
    const float* b_ff1  = (const float*)d_in[12];
    const float* W_ff2  = (const float*)d_in[13];
    const float* b_ff2  = (const float*)d_in[14];
    float* out = (float*)d_out;

    char* ws = (char*)d_ws;
    size_t off = 0;
    auto alloc = [&](size_t b) {
        char* p = ws + off;
        off += (b + 255) & ~(size_t)255;
        return p;
    };
    ushort_t* Wl1t  = (ushort_t*)alloc(2048ull * 1024 * 2);
    ushort_t* Wl2t  = (ushort_t*)alloc(1024ull * 1024 * 2);
    ushort_t* Wff1t = (ushort_t*)alloc(4096ull * 1024 * 2);
    ushort_t* Wff2t = (ushort_t*)alloc(1024ull * 4096 * 2);
    char* regA = alloc(134217728ull);          // t1 / conv-out / ffn1-out
    ushort_t* B1 = (ushort_t*)alloc(33554432ull); // h1 / g / h2
    ushort_t* t1   = (ushort_t*)regA;
    ushort_t* cbuf = (ushort_t*)regA;
    ushort_t* f1   = (ushort_t*)regA;

    const int R = 16384;  // B*S rows

    trans_k<<<dim3(16, 32), 256, 0, stream>>>(W_l1, Wl1t, 1024, 2048);
    trans_k<<<dim3(16, 16), 256, 0, stream>>>(W_l2, Wl2t, 1024, 1024);
    trans_k<<<dim3(16, 64), 256, 0, stream>>>(W_ff1, Wff1t, 1024, 4096);
    trans_k<<<dim3(64, 16), 256, 0, stream>>>(W_ff2, Wff2t, 4096, 1024);

    // sublayer 1: norm -> GEMM(D,2D)+bias -> GLU*mask -> conv -> GEMM(D,D)+bias+res
    norm_k<<<R, 256, 0, stream>>>(x, alpha1, bias1, B1);
    gemm_k<0><<<128 * 16, 256, 0, stream>>>(B1, Wl1t, b_l1, nullptr, nullptr, t1, 2048, 1024);
    glu_k<<<8192, 256, 0, stream>>>(t1, mask, B1);
    conv_k<<<8192, 256, 0, stream>>>(B1, conv_w, cbuf);
    gemm_k<1><<<128 * 8, 256, 0, stream>>>(cbuf, Wl2t, b_l2, x, out, nullptr, 1024, 1024);

    // sublayer 2: norm -> GEMM(D,DFF)+bias+relu -> GEMM(DFF,D)+bias+res
    norm_k<<<R, 256, 0, stream>>>(out, alpha2, bias2, B1);
    gemm_k<2><<<128 * 32, 256, 0, stream>>>(B1, Wff1t, b_ff1, nullptr, nullptr, f1, 4096, 1024);
    gemm_k<1><<<128 * 8, 256, 0, stream>>>(f1, Wff2t, b_ff2, out, out, nullptr, 1024, 4096);
}

// Round 2
// 639.020 us; speedup vs baseline: 1.1276x; 1.1276x over previous
//
#include <hip/hip_runtime.h>

typedef unsigned short ushort_t;
typedef __attribute__((ext_vector_type(8))) short s8v;
typedef __attribute__((ext_vector_type(4))) float f4v;

__device__ __forceinline__ float b2f(ushort_t h) {
    union { unsigned u; float f; } c; c.u = ((unsigned)h) << 16; return c.f;
}
__device__ __forceinline__ ushort_t f2b(float f) {
    union { float f; unsigned u; } c; c.f = f;
    unsigned u = c.u;
    return (ushort_t)((u + 0x7fffu + ((u >> 16) & 1u)) >> 16);
}

__device__ __forceinline__ void glds16(const void* g, void* l) {
    __builtin_amdgcn_global_load_lds(
        (const __attribute__((address_space(1))) void*)g,
        (__attribute__((address_space(3))) void*)l, 16, 0, 0);
}

// ---------------- weight transpose f32 [K,N] -> bf16 [N,K] ----------------
__global__ __launch_bounds__(256) void trans_k(const float* __restrict__ W,
                                               ushort_t* __restrict__ Wt,
                                               int K, int N) {
    __shared__ float tile[64][65];
    int k0 = blockIdx.x * 64, n0 = blockIdx.y * 64;
    int t = threadIdx.x;
    int c = t & 63, r4 = t >> 6;
#pragma unroll
    for (int i = 0; i < 16; ++i) {
        int r = i * 4 + r4;
        tile[r][c] = W[(size_t)(k0 + r) * N + n0 + c];
    }
    __syncthreads();
#pragma unroll
    for (int i = 0; i < 16; ++i) {
        int r = i * 4 + r4;
        Wt[(size_t)(n0 + r) * K + k0 + c] = f2b(tile[c][r]);
    }
}

// ---------------- norm: alpha*(x-mu)/(std_ddof1+eps)+bias -> bf16 --------
__global__ __launch_bounds__(256) void norm_k(const float* __restrict__ x,
                                              const float* __restrict__ al,
                                              const float* __restrict__ be,
                                              ushort_t* __restrict__ out) {
    int row = blockIdx.x;
    const float4* xr = (const float4*)(x + (size_t)row * 1024);
    float4 v = xr[threadIdx.x];
    float s = v.x + v.y + v.z + v.w;
    float q = v.x * v.x + v.y * v.y + v.z * v.z + v.w * v.w;
#pragma unroll
    for (int o = 32; o > 0; o >>= 1) {
        s += __shfl_down(s, o);
        q += __shfl_down(q, o);
    }
    __shared__ float ss[4], qq[4];
    int lane = threadIdx.x & 63, wv = threadIdx.x >> 6;
    if (lane == 0) { ss[wv] = s; qq[wv] = q; }
    __syncthreads();
    s = ss[0] + ss[1] + ss[2] + ss[3];
    q = qq[0] + qq[1] + qq[2] + qq[3];
    float mu = s * (1.f / 1024.f);
    float var = (q - 1024.f * mu * mu) * (1.f / 1023.f);
    var = fmaxf(var, 0.f);
    float inv = 1.f / (sqrtf(var) + 1e-6f);
    float4 a4 = ((const float4*)al)[threadIdx.x];
    float4 b4 = ((const float4*)be)[threadIdx.x];
    ushort4 o4;
    o4.x = f2b(a4.x * (v.x - mu) * inv + b4.x);
    o4.y = f2b(a4.y * (v.y - mu) * inv + b4.y);
    o4.z = f2b(a4.z * (v.z - mu) * inv + b4.z);
    o4.w = f2b(a4.w * (v.w - mu) * inv + b4.w);
    ((ushort4*)(out + (size_t)row * 1024))[threadIdx.x] = o4;
}

// ---------------- GLU + mask: g = a*sigmoid(b)*mask -----------------------
__global__ __launch_bounds__(256) void glu_k(const ushort_t* __restrict__ t1,
                                             const int* __restrict__ mask,
                                             ushort_t* __restrict__ g) {
    int i = blockIdx.x * 256 + threadIdx.x;
    int row = i >> 7;
    int cc = (i & 127) << 3;
    int b = row >> 10, s = row & 1023;
    size_t base = (size_t)row * 2048;
    s8v va = *(const s8v*)(t1 + base + cc);
    s8v vb = *(const s8v*)(t1 + base + 1024 + cc);
    float mval = (mask[b * 1024 + s] == 0) ? 0.f : 1.f;
    s8v ov;
#pragma unroll
    for (int j = 0; j < 8; ++j) {
        float a = b2f((ushort_t)va[j]);
        float xx = b2f((ushort_t)vb[j]);
        float sg = 1.f / (1.f + __expf(-xx));
        ov[j] = (short)f2b(a * sg * mval);
    }
    *(s8v*)(g + (size_t)row * 1024 + cc) = ov;
}

// ---------------- depthwise lightconv K=3, softmax weights ----------------
__global__ __launch_bounds__(256) void conv_k(const ushort_t* __restrict__ g,
                                              const float* __restrict__ cw,
                                              ushort_t* __restrict__ out) {
    int i = blockIdx.x * 256 + threadIdx.x;
    int row = i >> 7;
    int cc = (i & 127) << 3;
    int s = row & 1023;
    int head = cc >> 6;
    float w0 = cw[head * 3 + 0], w1 = cw[head * 3 + 1], w2 = cw[head * 3 + 2];
    float mx = fmaxf(w0, fmaxf(w1, w2));
    float e0 = __expf(w0 - mx), e1 = __expf(w1 - mx), e2 = __expf(w2 - mx);
    float inv = 1.f / (e0 + e1 + e2);
    w0 = e0 * inv; w1 = e1 * inv; w2 = e2 * inv;
    size_t base = (size_t)row * 1024 + cc;
    s8v z = {0, 0, 0, 0, 0, 0, 0, 0};
    s8v vm = (s > 0)    ? *(const s8v*)(g + base - 1024) : z;
    s8v v0 = *(const s8v*)(g + base);
    s8v vp = (s < 1023) ? *(const s8v*)(g + base + 1024) : z;
    s8v ov;
#pragma unroll
    for (int j = 0; j < 8; ++j) {
        float r = w0 * b2f((ushort_t)vm[j]) + w1 * b2f((ushort_t)v0[j]) +
                  w2 * b2f((ushort_t)vp[j]);
        ov[j] = (short)f2b(r);
    }
    *(s8v*)(out + base) = ov;
}

// ---------------- bf16 GEMM, 256x256 tile, BK=32, 4-buffer ring pipeline --
// A [M,K] bf16 rm; Bt [N,K] bf16 rm. 512 threads = 8 waves (2M x 4N).
// LDS: 4 buffers x 32KB {A 256x32 (16KB), B 256x32 (16KB)}, XOR-swizzled.
// Pipeline: read kt i from buf[i%4], stage kt i+3 into buf[(i+3)%4],
// counted s_waitcnt vmcnt(8) once per K-tile (never 0 in main loop).
// EPI: 0 = bf16 out (+bias); 1 = f32 out (+bias+res); 2 = bf16 relu(+bias)
template <int EPI>
__global__ __launch_bounds__(512, 2) void gemm_k(const ushort_t* __restrict__ A,
                                                 const ushort_t* __restrict__ Bt,
                                                 const float* __restrict__ bias,
                                                 const float* res, float* outf,
                                                 ushort_t* outb, int N, int K) {
    __shared__ char smem[131072] __attribute__((aligned(128)));
    const int NBN = N >> 8;
    const int nwg = gridDim.x;          // 64 * NBN, divisible by 8
    const int per = nwg >> 3;
    const int tt = (blockIdx.x & 7) * per + (blockIdx.x >> 3);  // XCD strips
    const int gw = NBN << 3;            // GROUP_M = 8
    const int g = tt / gw;
    const int rem = tt - g * gw;
    const int bm = (g << 3) + (rem & 7);
    const int bn = rem >> 3;

    const int t = threadIdx.x;
    const int l = t & 63, w = t >> 6;
    const int wm = w >> 2, wn = w & 3;
    const int lr = l & 15, lk = l >> 4;

    // ---- staging (global -> LDS): linear dest, inverse-swizzled source ----
    // thread t covers row (t>>2) [+128 for 2nd chunk], 16B slot (t&3);
    // source col slot = (t&3) ^ ((t>>3)&3)  (= read-side swizzle inverse)
    const int swzel = (((t & 3) ^ ((t >> 3) & 3)) << 3);  // elements
    const int r0 = t >> 2;
    const ushort_t* pA0 = A + (size_t)(bm * 256 + r0) * K + swzel;
    const ushort_t* pA1 = pA0 + (size_t)128 * K;
    const ushort_t* pB0 = Bt + (size_t)(bn * 256 + r0) * K + swzel;
    const ushort_t* pB1 = pB0 + (size_t)128 * K;

    // ---- fragment ds_read offsets (swizzled), constant across K-tiles ----
    const int fswz = ((lk ^ ((lr >> 1) & 3)) << 4);
    int aoff[8], boff[4];
#pragma unroll
    for (int m = 0; m < 8; ++m)
        aoff[m] = (wm * 128 + m * 16 + lr) * 64 + fswz;
#pragma unroll
    for (int n = 0; n < 4; ++n)
        boff[n] = 16384 + (wn * 64 + n * 16 + lr) * 64 + fswz;

    f4v acc[8][4];
#pragma unroll
    for (int m = 0; m < 8; ++m)
#pragma unroll
        for (int n = 0; n < 4; ++n) acc[m][n] = f4v{0.f, 0.f, 0.f, 0.f};

    const int NK = K >> 5;

    // ---- prologue: stage kt 0,1,2 into buf 0,1,2 (12 loads) ----
    for (int p = 0; p < 3; ++p) {
        char* d = smem + p * 32768 + t * 16;
        glds16(pA0 + p * 32, d);
        glds16(pA1 + p * 32, d + 8192);
        glds16(pB0 + p * 32, d + 16384);
        glds16(pB1 + p * 32, d + 24576);
    }
    asm volatile("s_waitcnt vmcnt(8)" ::: "memory");
    __builtin_amdgcn_sched_barrier(0);
    __builtin_amdgcn_s_barrier();

    for (int i = 0; i < NK; ++i) {
        const char* cb = smem + (size_t)(i & 3) * 32768;
        int st = i + 3; if (st >= NK) st = NK - 1;   // tail: re-stage hot tile
        char* sbd = smem + (size_t)((i + 3) & 3) * 32768 + t * 16;
        const int ko = st * 32;

        // ---------------- phase A: m0..3 x n0..3 ----------------
        s8v a[4], b[4];
#pragma unroll
        for (int m = 0; m < 4; ++m) a[m] = *(const s8v*)(cb + aoff[m]);
#pragma unroll
        for (int n = 0; n < 4; ++n) b[n] = *(const s8v*)(cb + boff[n]);
        glds16(pA0 + ko, sbd);
        glds16(pA1 + ko, sbd + 8192);
        __builtin_amdgcn_s_barrier();
        asm volatile("s_waitcnt lgkmcnt(0)" ::: "memory");
        __builtin_amdgcn_sched_barrier(0);
        __builtin_amdgcn_s_setprio(1);
#pragma unroll
        for (int m = 0; m < 4; ++m)
#pragma unroll
            for (int n = 0; n < 4; ++n)
                acc[m][n] = __builtin_amdgcn_mfma_f32_16x16x32_bf16(
                    a[m], b[n], acc[m][n], 0, 0, 0);
        __builtin_amdgcn_s_setprio(0);
        __builtin_amdgcn_sched_barrier(0);
        __builtin_amdgcn_s_barrier();

        // ---------------- phase B: m4..7 x n0..3 ----------------
#pragma unroll
        for (int m = 0; m < 4; ++m) a[m] = *(const s8v*)(cb + aoff[4 + m]);
        glds16(pB0 + ko, sbd + 16384);
        glds16(pB1 + ko, sbd + 24576);
        __builtin_amdgcn_s_barrier();
        asm volatile("s_waitcnt lgkmcnt(0)" ::: "memory");
        __builtin_amdgcn_sched_barrier(0);
        __builtin_amdgcn_s_setprio(1);
#pragma unroll
        for (int m = 0; m < 4; ++m)
#pragma unroll
            for (int n = 0; n < 4; ++n)
                acc[4 + m][n] = __builtin_amdgcn_mfma_f32_16x16x32_bf16(
                    a[m], b[n], acc[4 + m][n], 0, 0, 0);
        __builtin_amdgcn_s_setprio(0);
        asm volatile("s_waitcnt vmcnt(8)" ::: "memory");   // drain kt i+1 only
        __builtin_amdgcn_sched_barrier(0);
        __builtin_amdgcn_s_barrier();
    }

    // ---------------- epilogue ----------------
#pragma unroll
    for (int n = 0; n < 4; ++n) {
        int gcol = bn * 256 + wn * 64 + n * 16 + lr;
        float bb = bias[gcol];
#pragma unroll
        for (int m = 0; m < 8; ++m) {
#pragma unroll
            for (int r = 0; r < 4; ++r) {
                int grow = bm * 256 + wm * 128 + m * 16 + lk * 4 + r;
                size_t oi = (size_t)grow * N + gcol;
                float v = acc[m][n][r] + bb;
                if (EPI == 1) {
                    outf[oi] = v + res[oi];
                } else if (EPI == 2) {
                    outb[oi] = f2b(fmaxf(v, 0.f));
                } else {
                    outb[oi] = f2b(v);
                }
            }
        }
    }
}

extern "C" void kernel_launch(void* const* d_in, const int* in_sizes, int n_in,
                              void* d_out, int out_size, void* d_ws, size_t ws_size,
                              hipStream_t stream) {
    const float* x      = (const float*)d_in[0];
    const int*   mask   = (const int*)d_in[1];
    const float* alpha1 = (const float*)d_in[2];
    const float* bias1  = (const float*)d_in[3];
    const float* alpha2 = (const float*)d_in[4];
    const float* bias2  = (const float*)d_in[5];
    const float* W_l1   = (const float*)d_in[6];
    const float* b_l1   = (const float*)d_in[7];
    const float* conv_w = (const float*)d_in[8];
    const float* W_l2   = (const float*)d_in[9];
    const float* b_l2   = (const float*)d_in[10];
    const float* W_ff1  = (const float*)d_in[11];
    const float* b_ff1  = (const float*)d_in[12];
    const float* W_ff2  = (const float*)d_in[13];
    const float* b_ff2  = (const float*)d_in[14];
    float* out = (float*)d_out;

    char* ws = (char*)d_ws;
    size_t off = 0;
    auto alloc = [&](size_t b) {
        char* p = ws + off;
        off += (b + 255) & ~(size_t)255;
        return p;
    };
    ushort_t* Wl1t  = (ushort_t*)alloc(2048ull * 1024 * 2);
    ushort_t* Wl2t  = (ushort_t*)alloc(1024ull * 1024 * 2);
    ushort_t* Wff1t = (ushort_t*)alloc(4096ull * 1024 * 2);
    ushort_t* Wff2t = (ushort_t*)alloc(1024ull * 4096 * 2);
    char* regA = alloc(134217728ull);             // t1 / ffn1-out
    ushort_t* B1 = (ushort_t*)alloc(33554432ull); // h1 / g / h2
    ushort_t* C1 = (ushort_t*)alloc(33554432ull); // conv-out
    ushort_t* t1 = (ushort_t*)regA;
    ushort_t* f1 = (ushort_t*)regA;

    const int R = 16384;  // B*S rows

    trans_k<<<dim3(16, 32), 256, 0, stream>>>(W_l1, Wl1t, 1024, 2048);
    trans_k<<<dim3(16, 16), 256, 0, stream>>>(W_l2, Wl2t, 1024, 1024);
    trans_k<<<dim3(16, 64), 256, 0, stream>>>(W_ff1, Wff1t, 1024, 4096);
    trans_k<<<dim3(64, 16), 256, 0, stream>>>(W_ff2, Wff2t, 4096, 1024);

    // sublayer 1: norm -> GEMM(D,2D)+bias -> GLU*mask -> conv -> GEMM(D,D)+bias+res
    norm_k<<<R, 256, 0, stream>>>(x, alpha1, bias1, B1);
    gemm_k<0><<<64 * 8, 512, 0, stream>>>(B1, Wl1t, b_l1, nullptr, nullptr, t1, 2048, 1024);
    glu_k<<<8192, 256, 0, stream>>>(t1, mask, B1);
    conv_k<<<8192, 256, 0, stream>>>(B1, conv_w, C1);
    gemm_k<1><<<64 * 4, 512, 0, stream>>>(C1, Wl2t, b_l2, x, out, nullptr, 1024, 1024);

    // sublayer 2: norm -> GEMM(D,DFF)+bias+relu -> GEMM(DFF,D)+bias+res
    norm_k<<<R, 256, 0, stream>>>(out, alpha2, bias2, B1);
    gemm_k<2><<<64 * 16, 512, 0, stream>>>(B1, Wff1t, b_ff1, nullptr, nullptr, f1, 4096, 1024);
    gemm_k<1><<<64 * 4, 512, 0, stream>>>(f1, Wff2t, b_ff2, out, out, nullptr, 1024, 4096);
}

// Round 3
// 575.201 us; speedup vs baseline: 1.2527x; 1.1109x over previous
//
#include <hip/hip_runtime.h>

typedef unsigned short ushort_t;
typedef __attribute__((ext_vector_type(8))) short s8v;
typedef __attribute__((ext_vector_type(4))) float f4v;

__device__ __forceinline__ float b2f(ushort_t h) {
    union { unsigned u; float f; } c; c.u = ((unsigned)h) << 16; return c.f;
}
__device__ __forceinline__ ushort_t f2b(float f) {
    union { float f; unsigned u; } c; c.f = f;
    unsigned u = c.u;
    return (ushort_t)((u + 0x7fffu + ((u >> 16) & 1u)) >> 16);
}

__device__ __forceinline__ void glds16(const void* g, void* l) {
    __builtin_amdgcn_global_load_lds(
        (const __attribute__((address_space(1))) void*)g,
        (__attribute__((address_space(3))) void*)l, 16, 0, 0);
}

// ---------------- weight transpose f32 [K,N] -> bf16 [N,K] ----------------
__global__ __launch_bounds__(256) void trans_k(const float* __restrict__ W,
                                               ushort_t* __restrict__ Wt,
                                               int K, int N) {
    __shared__ float tile[64][65];
    int k0 = blockIdx.x * 64, n0 = blockIdx.y * 64;
    int t = threadIdx.x;
    int c = t & 63, r4 = t >> 6;
#pragma unroll
    for (int i = 0; i < 16; ++i) {
        int r = i * 4 + r4;
        tile[r][c] = W[(size_t)(k0 + r) * N + n0 + c];
    }
    __syncthreads();
#pragma unroll
    for (int i = 0; i < 16; ++i) {
        int r = i * 4 + r4;
        Wt[(size_t)(n0 + r) * K + k0 + c] = f2b(tile[c][r]);
    }
}

// ---------------- norm: alpha*(x-mu)/(std_ddof1+eps)+bias -> bf16 --------
__global__ __launch_bounds__(256) void norm_k(const float* __restrict__ x,
                                              const float* __restrict__ al,
                                              const float* __restrict__ be,
                                              ushort_t* __restrict__ out) {
    int row = blockIdx.x;
    const float4* xr = (const float4*)(x + (size_t)row * 1024);
    float4 v = xr[threadIdx.x];
    float s = v.x + v.y + v.z + v.w;
    float q = v.x * v.x + v.y * v.y + v.z * v.z + v.w * v.w;
#pragma unroll
    for (int o = 32; o > 0; o >>= 1) {
        s += __shfl_down(s, o);
        q += __shfl_down(q, o);
    }
    __shared__ float ss[4], qq[4];
    int lane = threadIdx.x & 63, wv = threadIdx.x >> 6;
    if (lane == 0) { ss[wv] = s; qq[wv] = q; }
    __syncthreads();
    s = ss[0] + ss[1] + ss[2] + ss[3];
    q = qq[0] + qq[1] + qq[2] + qq[3];
    float mu = s * (1.f / 1024.f);
    float var = (q - 1024.f * mu * mu) * (1.f / 1023.f);
    var = fmaxf(var, 0.f);
    float inv = 1.f / (sqrtf(var) + 1e-6f);
    float4 a4 = ((const float4*)al)[threadIdx.x];
    float4 b4 = ((const float4*)be)[threadIdx.x];
    ushort4 o4;
    o4.x = f2b(a4.x * (v.x - mu) * inv + b4.x);
    o4.y = f2b(a4.y * (v.y - mu) * inv + b4.y);
    o4.z = f2b(a4.z * (v.z - mu) * inv + b4.z);
    o4.w = f2b(a4.w * (v.w - mu) * inv + b4.w);
    ((ushort4*)(out + (size_t)row * 1024))[threadIdx.x] = o4;
}

// ---------------- GLU + mask: g = a*sigmoid(b)*mask -----------------------
__global__ __launch_bounds__(256) void glu_k(const ushort_t* __restrict__ t1,
                                             const int* __restrict__ mask,
                                             ushort_t* __restrict__ g) {
    int i = blockIdx.x * 256 + threadIdx.x;
    int row = i >> 7;
    int cc = (i & 127) << 3;
    int b = row >> 10, s = row & 1023;
    size_t base = (size_t)row * 2048;
    s8v va = *(const s8v*)(t1 + base + cc);
    s8v vb = *(const s8v*)(t1 + base + 1024 + cc);
    float mval = (mask[b * 1024 + s] == 0) ? 0.f : 1.f;
    s8v ov;
#pragma unroll
    for (int j = 0; j < 8; ++j) {
        float a = b2f((ushort_t)va[j]);
        float xx = b2f((ushort_t)vb[j]);
        float sg = 1.f / (1.f + __expf(-xx));
        ov[j] = (short)f2b(a * sg * mval);
    }
    *(s8v*)(g + (size_t)row * 1024 + cc) = ov;
}

// ---------------- depthwise lightconv K=3, softmax weights ----------------
__global__ __launch_bounds__(256) void conv_k(const ushort_t* __restrict__ g,
                                              const float* __restrict__ cw,
                                              ushort_t* __restrict__ out) {
    int i = blockIdx.x * 256 + threadIdx.x;
    int row = i >> 7;
    int cc = (i & 127) << 3;
    int s = row & 1023;
    int head = cc >> 6;
    float w0 = cw[head * 3 + 0], w1 = cw[head * 3 + 1], w2 = cw[head * 3 + 2];
    float mx = fmaxf(w0, fmaxf(w1, w2));
    float e0 = __expf(w0 - mx), e1 = __expf(w1 - mx), e2 = __expf(w2 - mx);
    float inv = 1.f / (e0 + e1 + e2);
    w0 = e0 * inv; w1 = e1 * inv; w2 = e2 * inv;
    size_t base = (size_t)row * 1024 + cc;
    s8v z = {0, 0, 0, 0, 0, 0, 0, 0};
    s8v vm = (s > 0)    ? *(const s8v*)(g + base - 1024) : z;
    s8v v0 = *(const s8v*)(g + base);
    s8v vp = (s < 1023) ? *(const s8v*)(g + base + 1024) : z;
    s8v ov;
#pragma unroll
    for (int j = 0; j < 8; ++j) {
        float r = w0 * b2f((ushort_t)vm[j]) + w1 * b2f((ushort_t)v0[j]) +
                  w2 * b2f((ushort_t)vp[j]);
        ov[j] = (short)f2b(r);
    }
    *(s8v*)(out + base) = ov;
}

// ---------------- bf16 GEMM, 256x256 tile, BK=32, phase-pipelined --------
// A [M,K] bf16 rm; Bt [N,K] bf16 rm. 512 threads = 8 waves (2M x 4N).
// LDS: ring-4 x 32KB {A 16KB, B 16KB}, XOR-swizzled both sides.
// Per K-tile: P0 reads AH_i (next phase's operands pattern), MFMA low-half
// with regs read one phase earlier; P1 reads AL/B of tile i+1, MFMA high.
// Counted lgkmcnt(4/8); vmcnt(6) once per K-tile, before a barrier.
// EPI: 0 = bf16 out (+bias); 1 = f32 out (+bias+res); 2 = bf16 relu(+bias)
template <int EPI>
__global__ __launch_bounds__(512, 2) void gemm_k(const ushort_t* __restrict__ A,
                                                 const ushort_t* __restrict__ Bt,
                                                 const float* __restrict__ bias,
                                                 const float* res, float* outf,
                                                 ushort_t* outb, int N, int K) {
    __shared__ char smem[131072] __attribute__((aligned(128)));
    const int NBN = N >> 8;
    const int nwg = gridDim.x;
    const int per = nwg >> 3;
    const int tt = (blockIdx.x & 7) * per + (blockIdx.x >> 3);  // XCD strips
    const int gw = NBN << 3;            // GROUP_M = 8
    const int g = tt / gw;
    const int rem = tt - g * gw;
    const int bm = (g << 3) + (rem & 7);
    const int bn = rem >> 3;

    const int t = threadIdx.x;
    const int l = t & 63, w = t >> 6;
    const int wm = w >> 2, wn = w & 3;
    const int lr = l & 15, lk = l >> 4;

    // staging: linear LDS dest, inverse-swizzled global source
    const int swzel = (((t & 3) ^ ((t >> 3) & 3)) << 3);
    const int r0 = t >> 2;
    const ushort_t* pA0 = A + (size_t)(bm * 256 + r0) * K + swzel;
    const ushort_t* pA1 = pA0 + (size_t)128 * K;
    const ushort_t* pB0 = Bt + (size_t)(bn * 256 + r0) * K + swzel;
    const ushort_t* pB1 = pB0 + (size_t)128 * K;

    const int fswz = ((lk ^ ((lr >> 1) & 3)) << 4);
    int aoffL[4], aoffH[4], boff[4];
#pragma unroll
    for (int m = 0; m < 4; ++m) {
        aoffL[m] = (wm * 128 + m * 16 + lr) * 64 + fswz;
        aoffH[m] = (wm * 128 + (4 + m) * 16 + lr) * 64 + fswz;
        boff[m] = 16384 + (wn * 64 + m * 16 + lr) * 64 + fswz;
    }

    f4v acc[8][4];
#pragma unroll
    for (int m = 0; m < 8; ++m)
#pragma unroll
        for (int n = 0; n < 4; ++n) acc[m][n] = f4v{0.f, 0.f, 0.f, 0.f};

    const int NK = K >> 5;

    // ---- prologue: stage tiles 0,1,2 ----
#pragma unroll
    for (int p = 0; p < 3; ++p) {
        char* d = smem + p * 32768 + t * 16;
        glds16(pA0 + p * 32, d);
        glds16(pA1 + p * 32, d + 8192);
        glds16(pB0 + p * 32, d + 16384);
        glds16(pB1 + p * 32, d + 24576);
    }
    asm volatile("s_waitcnt vmcnt(8)" ::: "memory");   // tile 0 landed
    __builtin_amdgcn_sched_barrier(0);
    __builtin_amdgcn_s_barrier();

    s8v aL0[4], bC0[4], aL1[4], bC1[4], aH[4];
#pragma unroll
    for (int m = 0; m < 4; ++m) aL0[m] = *(const s8v*)(smem + aoffL[m]);
#pragma unroll
    for (int n = 0; n < 4; ++n) bC0[n] = *(const s8v*)(smem + boff[n]);

#define KSTEP(I, CAL, CB, NAL, NB)                                             \
    {                                                                          \
        const int i_ = (I);                                                    \
        const char* cb_ = smem + (size_t)(i_ & 3) * 32768;                     \
        const int nx_ = (i_ + 1 < NK) ? i_ + 1 : NK - 1;                       \
        const char* nb_ = smem + (size_t)(nx_ & 3) * 32768;                    \
        int st_ = i_ + 3; if (st_ >= NK) st_ = NK - 1;                         \
        char* sd_ = smem + (size_t)((i_ + 3) & 3) * 32768 + t * 16;            \
        const int ko_ = st_ * 32;                                              \
        /* ---- P0 ---- */                                                     \
        _Pragma("unroll")                                                      \
        for (int m = 0; m < 4; ++m) aH[m] = *(const s8v*)(cb_ + aoffH[m]);     \
        glds16(pA0 + ko_, sd_);                                                \
        glds16(pA1 + ko_, sd_ + 8192);                                         \
        asm volatile("s_waitcnt vmcnt(6)" ::: "memory");                       \
        __builtin_amdgcn_sched_barrier(0);                                     \
        __builtin_amdgcn_s_barrier();                                          \
        asm volatile("s_waitcnt lgkmcnt(4)" ::: "memory");                     \
        __builtin_amdgcn_sched_barrier(0);                                     \
        __builtin_amdgcn_s_setprio(1);                                         \
        _Pragma("unroll")                                                      \
        for (int m = 0; m < 4; ++m)                                            \
            _Pragma("unroll")                                                  \
            for (int n = 0; n < 4; ++n)                                        \
                acc[m][n] = __builtin_amdgcn_mfma_f32_16x16x32_bf16(           \
                    CAL[m], CB[n], acc[m][n], 0, 0, 0);                        \
        __builtin_amdgcn_s_setprio(0);                                         \
        __builtin_amdgcn_sched_barrier(0);                                     \
        __builtin_amdgcn_s_barrier();                                          \
        /* ---- P1 ---- */                                                     \
        _Pragma("unroll")                                                      \
        for (int m = 0; m < 4; ++m) NAL[m] = *(const s8v*)(nb_ + aoffL[m]);    \
        _Pragma("unroll")                                                      \
        for (int n = 0; n < 4; ++n) NB[n] = *(const s8v*)(nb_ + boff[n]);      \
        glds16(pB0 + ko_, sd_ + 16384);                                        \
        glds16(pB1 + ko_, sd_ + 24576);                                        \
        __builtin_amdgcn_s_barrier();                                          \
        asm volatile("s_waitcnt lgkmcnt(8)" ::: "memory");                     \
        __builtin_amdgcn_sched_barrier(0);                                     \
        __builtin_amdgcn_s_setprio(1);                                         \
        _Pragma("unroll")                                                      \
        for (int m = 0; m < 4; ++m)                                            \
            _Pragma("unroll")                                                  \
            for (int n = 0; n < 4; ++n)                                        \
                acc[4 + m][n] = __builtin_amdgcn_mfma_f32_16x16x32_bf16(       \
                    aH[m], CB[n], acc[4 + m][n], 0, 0, 0);                     \
        __builtin_amdgcn_s_setprio(0);                                         \
        __builtin_amdgcn_sched_barrier(0);                                     \
        __builtin_amdgcn_s_barrier();                                          \
    }

    for (int ii = 0; ii < NK; ii += 2) {
        KSTEP(ii, aL0, bC0, aL1, bC1);
        KSTEP(ii + 1, aL1, bC1, aL0, bC0);
    }
#undef KSTEP

    // ---------------- epilogue ----------------
    if (EPI == 1) {
#pragma unroll
        for (int n = 0; n < 4; ++n) {
            int gcol = bn * 256 + wn * 64 + n * 16 + lr;
            float bb = bias[gcol];
#pragma unroll
            for (int m = 0; m < 8; ++m) {
#pragma unroll
                for (int r = 0; r < 4; ++r) {
                    int grow = bm * 256 + wm * 128 + m * 16 + lk * 4 + r;
                    size_t oi = (size_t)grow * N + gcol;
                    outf[oi] = acc[m][n][r] + bb + res[oi];
                }
            }
        }
    } else {
        // drain stale staging, then reuse smem for coalesced bf16 stores
        asm volatile("s_waitcnt vmcnt(0)" ::: "memory");
        __builtin_amdgcn_s_barrier();
        float biasr[4];
#pragma unroll
        for (int n = 0; n < 4; ++n)
            biasr[n] = bias[bn * 256 + wn * 64 + n * 16 + lr];
        char* sB = smem;
#pragma unroll
        for (int half = 0; half < 2; ++half) {
#pragma unroll
            for (int m4 = 0; m4 < 4; ++m4)
#pragma unroll
                for (int n = 0; n < 4; ++n)
#pragma unroll
                    for (int r = 0; r < 4; ++r) {
                        int rl = wm * 64 + m4 * 16 + lk * 4 + r;
                        int cl = wn * 64 + n * 16 + lr;
                        float v = acc[half * 4 + m4][n][r] + biasr[n];
                        if (EPI == 2) v = fmaxf(v, 0.f);
                        int byt = rl * 512 + ((cl * 2) ^ ((rl & 3) << 4));
                        *(ushort_t*)(sB + byt) = f2b(v);
                    }
            __builtin_amdgcn_s_barrier();
#pragma unroll
            for (int s = 0; s < 8; ++s) {
                int rl = s * 16 + (t >> 5);
                int byt = rl * 512 + (((t & 31) * 16) ^ ((rl & 3) << 4));
                int grow = bm * 256 + (rl >> 6) * 128 + half * 64 + (rl & 63);
                int gcol = bn * 256 + (t & 31) * 8;
                *(s8v*)(outb + (size_t)grow * N + gcol) = *(const s8v*)(sB + byt);
            }
            __builtin_amdgcn_s_barrier();
        }
    }
}

extern "C" void kernel_launch(void* const* d_in, const int* in_sizes, int n_in,
                              void* d_out, int out_size, void* d_ws, size_t ws_size,
                              hipStream_t stream) {
    const float* x      = (const float*)d_in[0];
    const int*   mask   = (const int*)d_in[1];
    const float* alpha1 = (const float*)d_in[2];
    const float* bias1  = (const float*)d_in[3];
    const float* alpha2 = (const float*)d_in[4];
    const float* bias2  = (const float*)d_in[5];
    const float* W_l1   = (const float*)d_in[6];
    const float* b_l1   = (const float*)d_in[7];
    const float* conv_w = (const float*)d_in[8];
    const float* W_l2   = (const float*)d_in[9];
    const float* b_l2   = (const float*)d_in[10];
    const float* W_ff1  = (const float*)d_in[11];
    const float* b_ff1  = (const float*)d_in[12];
    const float* W_ff2  = (const float*)d_in[13];
    const float* b_ff2  = (const float*)d_in[14];
    float* out = (float*)d_out;

    char* ws = (char*)d_ws;
    size_t off = 0;
    auto alloc = [&](size_t b) {
        char* p = ws + off;
        off += (b + 255) & ~(size_t)255;
        return p;
    };
    ushort_t* Wl1t  = (ushort_t*)alloc(2048ull * 1024 * 2);
    ushort_t* Wl2t  = (ushort_t*)alloc(1024ull * 1024 * 2);
    ushort_t* Wff1t = (ushort_t*)alloc(4096ull * 1024 * 2);
    ushort_t* Wff2t = (ushort_t*)alloc(1024ull * 4096 * 2);
    char* regA = alloc(134217728ull);             // t1 / ffn1-out
    ushort_t* B1 = (ushort_t*)alloc(33554432ull); // h1 / g / h2
    ushort_t* C1 = (ushort_t*)alloc(33554432ull); // conv-out
    ushort_t* t1 = (ushort_t*)regA;
    ushort_t* f1 = (ushort_t*)regA;

    const int R = 16384;  // B*S rows

    trans_k<<<dim3(16, 32), 256, 0, stream>>>(W_l1, Wl1t, 1024, 2048);
    trans_k<<<dim3(16, 16), 256, 0, stream>>>(W_l2, Wl2t, 1024, 1024);
    trans_k<<<dim3(16, 64), 256, 0, stream>>>(W_ff1, Wff1t, 1024, 4096);
    trans_k<<<dim3(64, 16), 256, 0, stream>>>(W_ff2, Wff2t, 4096, 1024);

    // sublayer 1: norm -> GEMM(D,2D)+bias -> GLU*mask -> conv -> GEMM(D,D)+bias+res
    norm_k<<<R, 256, 0, stream>>>(x, alpha1, bias1, B1);
    gemm_k<0><<<64 * 8, 512, 0, stream>>>(B1, Wl1t, b_l1, nullptr, nullptr, t1, 2048, 1024);
    glu_k<<<8192, 256, 0, stream>>>(t1, mask, B1);
    conv_k<<<8192, 256, 0, stream>>>(B1, conv_w, C1);
    gemm_k<1><<<64 * 4, 512, 0, stream>>>(C1, Wl2t, b_l2, x, out, nullptr, 1024, 1024);

    // sublayer 2: norm -> GEMM(D,DFF)+bias+relu -> GEMM(DFF,D)+bias+res
    norm_k<<<R, 256, 0, stream>>>(out, alpha2, bias2, B1);
    gemm_k<2><<<64 * 16, 512, 0, stream>>>(B1, Wff1t, b_ff1, nullptr, nullptr, f1, 4096, 1024);
    gemm_k<1><<<64 * 4, 512, 0, stream>>>(f1, Wff2t, b_ff2, out, out, nullptr, 1024, 4096);
}